// Round 7
// baseline (446.098 us; speedup 1.0000x reference)
//
#include <hip/hip_runtime.h>

// RANGE2BEV: scatter range-view features (B,C,RH,RW) into BEV grid (B,C,D,W,H)
// with last-write-wins duplicate resolution (np fancy-assignment semantics).
//
//   pass 1: hipMemsetAsync winner = 0xFF (-1)
//   pass 2: per point, atomicMax(winner, i)   (largest point index wins)
//   pass 3: transpose feat (b,c,n) -> featT (b,n,c)   [float4 both sides]
//   pass 4: per 256-cell block: winners -> LDS, gather featT rows (256 B
//           contiguous float4 loads), LDS transpose, then per channel ONE
//           wave stores 1 KB contiguous (float4/lane) nontemporal.

namespace {

typedef float v4f __attribute__((ext_vector_type(4)));

constexpr int Wg    = 400;          // (40-(-40))/0.2
constexpr int Hg    = 352;          // (70.4-0)/0.2
constexpr int Dg    = 5;            // (1-(-3))/0.8
constexpr int NCELL = Dg * Wg * Hg; // 704000
constexpr int NPTS  = 64 * 2048;    // 131072 points per batch
constexpr int CC    = 64;
constexpr int BB    = 2;
constexpr int GRP   = 256;          // cells per block in bev pass
constexpr int NGRP  = NCELL / GRP;  // 2750

__global__ void scatter_winner_k(const float* __restrict__ xyz,
                                 int* __restrict__ winner) {
    int idx = blockIdx.x * blockDim.x + threadIdx.x;
    if (idx >= BB * NPTS) return;
    int b = idx >> 17;              // / NPTS (131072)
    int i = idx & (NPTS - 1);
    const float* base = xyz + (size_t)b * 3 * NPTS;
    float xp = base[i];
    float yp = base[NPTS + i];
    float zp = base[2 * NPTS + i];
    if (!(zp >= -3.0f && zp < 1.0f)) return;          // valid z: [-3, 1)
    int zbin  = (int)floorf((zp + 3.0f) / 0.8f);      // [0,4], same f32 math as ref
    int x_img = (int)(-yp / 0.2f) + 200;              // trunc-toward-zero, f32 div
    int y_img = (int)(-xp / 0.2f) + 352;
    x_img = min(max(x_img, 0), Wg - 1);
    y_img = min(max(y_img, 0), Hg - 1);
    int xf = (Wg - 1) - x_img;
    int yf = (Hg - 1) - y_img;
    int cell = (zbin * Wg + xf) * Hg + yf;
    atomicMax(winner + b * NCELL + cell, i);          // last (largest i) wins
}

// feat (b, c=64, n) -> featT (b, n, c=64); 64x64 tiles, float4 on both
// global sides, scalar LDS with pad-65 (2-way bank alias only -> free).
__global__ __launch_bounds__(256) void transpose_k(const float* __restrict__ feat,
                                                   float* __restrict__ featT) {
    __shared__ float tile[64][65];
    int blk = blockIdx.x;
    int b   = blk >> 11;                  // 2048 tiles per batch
    int n0  = (blk & 2047) * 64;
    const float* fb = feat  + (size_t)b * CC * NPTS;
    float*       tb = featT + (size_t)b * NPTS * CC;
    int t = threadIdx.x, w = t >> 6, l = t & 63;
    int sub = l >> 4, m = l & 15;         // 16 lanes per 64-float row
#pragma unroll
    for (int k = 0; k < 4; ++k) {
        int c = k * 16 + w * 4 + sub;     // row of feat
        v4f v = *reinterpret_cast<const v4f*>(fb + (size_t)c * NPTS + n0 + m * 4);
        tile[c][m * 4 + 0] = v.x;
        tile[c][m * 4 + 1] = v.y;
        tile[c][m * 4 + 2] = v.z;
        tile[c][m * 4 + 3] = v.w;
    }
    __syncthreads();
#pragma unroll
    for (int k = 0; k < 4; ++k) {
        int nn = k * 16 + w * 4 + sub;    // row of featT
        v4f v;
        v.x = tile[m * 4 + 0][nn];
        v.y = tile[m * 4 + 1][nn];
        v.z = tile[m * 4 + 2][nn];
        v.w = tile[m * 4 + 3][nn];
        *reinterpret_cast<v4f*>(tb + (size_t)(n0 + nn) * CC + m * 4) = v;
    }
}

// One block = 256 consecutive cells of one batch.
__global__ __launch_bounds__(256) void bev_write_k(const float* __restrict__ featT,
                                                   const int*   __restrict__ winner,
                                                   float*       __restrict__ out) {
    __shared__ float tile[GRP][65];       // [cell][channel], pad 65
    __shared__ int   wins[GRP];
    int blk   = blockIdx.x;
    int b     = blk / NGRP;
    int cell0 = (blk - b * NGRP) * GRP;
    int t     = threadIdx.x;
    int w     = t >> 6, l = t & 63;
    int sub   = l >> 4, m = l & 15;       // 16 lanes per 256 B featT row

    wins[t] = winner[b * NCELL + cell0 + t];          // 1 KB coalesced
    __syncthreads();

    const float* ftb = featT + (size_t)b * NPTS * CC;
    // stage A: gather; iteration k handles cells g = k*16 + w*4 + sub
#pragma unroll
    for (int k = 0; k < 16; ++k) {
        int g  = k * 16 + w * 4 + sub;
        int pt = wins[g];
        v4f v = {0.0f, 0.0f, 0.0f, 0.0f};
        if (pt >= 0)                                  // 16-lane-group predicate
            v = *reinterpret_cast<const v4f*>(ftb + (size_t)pt * CC + m * 4);
        tile[g][m * 4 + 0] = v.x;
        tile[g][m * 4 + 1] = v.y;
        tile[g][m * 4 + 2] = v.z;
        tile[g][m * 4 + 3] = v.w;
    }
    __syncthreads();
    // stage B: wave = one channel per iteration; 1 KB contiguous nt store
    float* ob = out + (size_t)b * CC * NCELL + cell0;
#pragma unroll
    for (int k = 0; k < 16; ++k) {
        int c = k * 4 + w;
        v4f v;
        v.x = tile[4 * l + 0][c];
        v.y = tile[4 * l + 1][c];
        v.z = tile[4 * l + 2][c];
        v.w = tile[4 * l + 3][c];
        __builtin_nontemporal_store(v, reinterpret_cast<v4f*>(ob + (size_t)c * NCELL + 4 * l));
    }
}

} // namespace

extern "C" void kernel_launch(void* const* d_in, const int* in_sizes, int n_in,
                              void* d_out, int out_size, void* d_ws, size_t ws_size,
                              hipStream_t stream) {
    const float* range_res = (const float*)d_in[0];   // (B,C,RH,RW) f32
    const float* xyz       = (const float*)d_in[1];   // (B,3,RH,RW) f32
    float* out             = (float*)d_out;           // (B,C,D,W,H) f32
    int*   winner          = (int*)d_ws;              // BB*NCELL ints = 5.6 MB
    float* featT           = (float*)((char*)d_ws + (8u << 20));  // 64 MB at +8 MB

    // winner = -1 via byte pattern 0xFF (graph-capturable memset node)
    (void)hipMemsetAsync(winner, 0xFF, (size_t)BB * NCELL * sizeof(int), stream);

    {
        int total = BB * NPTS;
        scatter_winner_k<<<(total + 255) / 256, 256, 0, stream>>>(xyz, winner);
    }
    {
        int blocks = BB * (NPTS / 64);                // 4096
        transpose_k<<<blocks, 256, 0, stream>>>(range_res, featT);
    }
    {
        int blocks = BB * NGRP;                       // 5500
        bev_write_k<<<blocks, 256, 0, stream>>>(featT, winner, out);
    }
}